// Round 7
// baseline (880.180 us; speedup 1.0000x reference)
//
#include <hip/hip_runtime.h>
#include <hip/hip_bf16.h>

// ---------------- sizes ----------------
#define BB   16
#define LL   1024
#define DM   128
#define DIN  256
#define NST  8
#define NROWS (BB*LL)      // 16384
#define NCH  32
#define TCH  32
#define PSZ  1048576       // B*NCH*DIN*8

static __device__ __forceinline__ float sigmoidf_(float x){ return 1.f/(1.f+expf(-x)); }
static __device__ __forceinline__ float siluf_(float x){ return x/(1.f+expf(-x)); }
static __device__ __forceinline__ unsigned short f2bf(float f){
    union { float f; unsigned u; } v; v.f = f;
    unsigned r = v.u + 0x7fff + ((v.u >> 16) & 1);
    return (unsigned short)(r >> 16);
}

typedef __attribute__((ext_vector_type(8))) short short8;
typedef __attribute__((ext_vector_type(4))) float floatx4;

// ---------------- LayerNorm -> f32 (PADDED transpose for decoder conv1) ----------------
__global__ __launch_bounds__(64) void ln_kernel(const float* __restrict__ X,
        const float* __restrict__ g, const float* __restrict__ b,
        float* __restrict__ Y, int transpose)
{
    int row = blockIdx.x;
    int t = threadIdx.x;
    float x0 = X[(long)row*DM + t];
    float x1 = X[(long)row*DM + 64 + t];
    float s = x0 + x1, ss = x0*x0 + x1*x1;
    #pragma unroll
    for (int off = 32; off; off >>= 1) { s += __shfl_down(s, off); ss += __shfl_down(ss, off); }
    s = __shfl(s, 0); ss = __shfl(ss, 0);
    float mean = s * (1.f/128.f);
    float var  = ss * (1.f/128.f) - mean*mean;
    float inv  = rsqrtf(var + 1e-5f);
    float y0 = (x0-mean)*inv*g[t]    + b[t];
    float y1 = (x1-mean)*inv*g[64+t] + b[64+t];
    if (!transpose) {
        Y[(long)row*DM + t] = y0;
        Y[(long)row*DM + 64 + t] = y1;
    } else {
        int bb = row >> 10, l = row & 1023;
        int r = l >> 5, c = l & 31;
        Y[((long)(bb*DM + t)*34 + (r+1))*34 + (c+1)]      = y0;
        Y[((long)(bb*DM + 64 + t)*34 + (r+1))*34 + (c+1)] = y1;
    }
}

// ---------------- LayerNorm -> bf16 (feeds MFMA GEMM) ----------------
__global__ __launch_bounds__(64) void ln_bf16_kernel(const float* __restrict__ X,
        const float* __restrict__ g, const float* __restrict__ b,
        unsigned short* __restrict__ Y)
{
    int row = blockIdx.x;
    int t = threadIdx.x;
    float x0 = X[(long)row*DM + t];
    float x1 = X[(long)row*DM + 64 + t];
    float s = x0 + x1, ss = x0*x0 + x1*x1;
    #pragma unroll
    for (int off = 32; off; off >>= 1) { s += __shfl_down(s, off); ss += __shfl_down(ss, off); }
    s = __shfl(s, 0); ss = __shfl(ss, 0);
    float mean = s * (1.f/128.f);
    float var  = ss * (1.f/128.f) - mean*mean;
    float inv  = rsqrtf(var + 1e-5f);
    Y[(long)row*DM + t]      = f2bf((x0-mean)*inv*g[t]    + b[t]);
    Y[(long)row*DM + 64 + t] = f2bf((x1-mean)*inv*g[64+t] + b[64+t]);
}

// ---------------- one-time weight f32->bf16 conversion ----------------
__global__ void wcvt(const float* __restrict__ Win, const float* __restrict__ Wout,
                     unsigned short* __restrict__ Wb)
{
    int t = blockIdx.x*256 + threadIdx.x;
    if (t < 196608) Wb[t] = f2bf(Win[t]);
    else if (t < 294912) Wb[t] = f2bf(Wout[t - 196608]);
}

// ---------------- bf16-MFMA GEMM: C[M,N] = A[M,K](bf16) @ W[N,K]^T(bf16) (+S) ----------------
template<int K, int MT>
__global__ __launch_bounds__(256) void gemm_bf16(const unsigned short* __restrict__ A,
        const unsigned short* __restrict__ Wb, const float* __restrict__ S,
        float* __restrict__ C, int N)
{
    constexpr int NMT = MT/64;
    __shared__ unsigned short Als[MT][40];
    __shared__ unsigned short Bls[128][40];
    const int tid = threadIdx.x;
    const int m0 = blockIdx.x * MT;
    const int n0 = blockIdx.y * 128;
    const int lane = tid & 63, wv = tid >> 6;
    const int fr = lane & 15, quad = lane >> 4;
    floatx4 acc[NMT][8];
    #pragma unroll
    for (int mt = 0; mt < NMT; mt++)
        #pragma unroll
        for (int nt = 0; nt < 8; nt++) acc[mt][nt] = (floatx4){0.f,0.f,0.f,0.f};
    for (int kc = 0; kc < K; kc += 32) {
        __syncthreads();
        #pragma unroll
        for (int u = tid; u < MT*4; u += 256) {          // A: bf16 16B vector copy
            int row = u >> 2, seg = u & 3;
            *(uint4*)&Als[row][seg*8] = *(const uint4*)&A[(long)(m0+row)*K + kc + seg*8];
        }
        #pragma unroll
        for (int u = tid; u < 512; u += 256) {           // W: bf16 16B vector copy
            int row = u >> 2, seg = u & 3;
            *(uint4*)&Bls[row][seg*8] = *(const uint4*)&Wb[(long)(n0+row)*K + kc + seg*8];
        }
        __syncthreads();
        short8 af[NMT];
        #pragma unroll
        for (int mt = 0; mt < NMT; mt++)
            af[mt] = *(const short8*)&Als[wv*(16*NMT) + mt*16 + fr][quad*8];
        #pragma unroll
        for (int nt = 0; nt < 8; nt++) {
            short8 bfv = *(const short8*)&Bls[nt*16 + fr][quad*8];
            #pragma unroll
            for (int mt = 0; mt < NMT; mt++)
                acc[mt][nt] = __builtin_amdgcn_mfma_f32_16x16x32_bf16(af[mt], bfv, acc[mt][nt], 0, 0, 0);
        }
    }
    const int rq = quad * 4;
    #pragma unroll
    for (int mt = 0; mt < NMT; mt++)
        #pragma unroll
        for (int nt = 0; nt < 8; nt++)
            #pragma unroll
            for (int r = 0; r < 4; r++) {
                long m = m0 + wv*(16*NMT) + mt*16 + rq + r;
                long n = n0 + nt*16 + fr;
                float v = acc[mt][nt][r];
                if (S) v += S[m*N + n];
                C[m*N + n] = v;
            }
}

// ---------------- fused depthwise conv+SiLU and x-proj/dt-proj/softplus ----------------
__global__ __launch_bounds__(256) void dwconv_xproj(const float* __restrict__ xz,
        const float* __restrict__ cw, const float* __restrict__ cb,
        const float* __restrict__ xproj_w, const float* __restrict__ dt_w,
        const float* __restrict__ dt_b, float* __restrict__ xc,
        float* __restrict__ dt_out, float* __restrict__ BC)
{
    __shared__ float xs[DIN];
    __shared__ float xdbl[24];
    int bl = blockIdx.x;            // b*1024 + l
    int d  = threadIdx.x;
    int l  = bl & 1023;
    float w0 = cw[d*4+0], w1 = cw[d*4+1], w2 = cw[d*4+2], w3 = cw[d*4+3];
    const float* base = xz + (long)bl*512 + d;
    float acc = cb[d] + w3 * base[0];
    if (l >= 1) acc += w2 * base[-512];
    if (l >= 2) acc += w1 * base[-1024];
    if (l >= 3) acc += w0 * base[-1536];
    float u = siluf_(acc);
    xs[d] = u;
    xc[(long)bl*DIN + d] = u;
    __syncthreads();
    int t = d;
    if (t < 192) {                       // 24 outputs x 8 lanes
        int e = t >> 3, j = t & 7;
        float p = 0.f;
        for (int k = j; k < DIN; k += 8) p += xs[k] * xproj_w[e*DIN + k];
        p += __shfl_down(p, 4, 8);
        p += __shfl_down(p, 2, 8);
        p += __shfl_down(p, 1, 8);
        if (j == 0) xdbl[e] = p;
    }
    __syncthreads();
    float v = dt_b[d];
    #pragma unroll
    for (int r = 0; r < 8; r++) v += xdbl[r] * dt_w[d*8 + r];
    v = (v > 20.f) ? v : log1pf(expf(v));           // softplus
    dt_out[(long)bl*DIN + d] = v;
    if (t < 16) BC[(long)bl*16 + t] = xdbl[8 + t];
}

// ---------------- chunked selective scan ----------------
__global__ __launch_bounds__(256) void scan_part(const float* __restrict__ dt,
        const float* __restrict__ xc, const float* __restrict__ BC,
        const float* __restrict__ Alog, float* __restrict__ PS)
{
    int b = blockIdx.x, c = blockIdx.y;
    int d = threadIdx.x;
    float a[NST], P[NST], S[NST];
    #pragma unroll
    for (int n = 0; n < NST; n++) { a[n] = -expf(Alog[d*NST + n]); P[n] = 1.f; S[n] = 0.f; }
    int t0 = c*TCH;
    const float* dtp = dt + ((long)b*LL + t0)*DIN + d;
    const float* up  = xc + ((long)b*LL + t0)*DIN + d;
    const float* bc  = BC + ((long)b*LL + t0)*16;
    for (int t = 0; t < TCH; t++) {
        float dtv = dtp[(long)t*DIN];
        float u   = up[(long)t*DIN];
        const float4* bc4 = (const float4*)(bc + t*16);
        float4 B0 = bc4[0], B1 = bc4[1];
        float Bv[NST] = {B0.x,B0.y,B0.z,B0.w,B1.x,B1.y,B1.z,B1.w};
        float dtu = dtv * u;
        #pragma unroll
        for (int n = 0; n < NST; n++) {
            float dA = __expf(dtv * a[n]);
            S[n] = dA * S[n] + dtu * Bv[n];
            P[n] *= dA;
        }
    }
    long o = (((long)b*NCH + c)*DIN + d)*8;
    #pragma unroll
    for (int n = 0; n < NST; n++) { PS[o + n] = P[n]; PS[PSZ + o + n] = S[n]; }
}

// parallelized over (b, n): 128 blocks, one (b,d,n) recurrence per thread.
__global__ __launch_bounds__(256) void scan_mid(const float* __restrict__ PS,
        float* __restrict__ Hinit)
{
    int b = blockIdx.x;
    int n = blockIdx.y;
    int d = threadIdx.x;
    float h = 0.f;
    for (int c = 0; c < NCH; c++) {
        long o = (((long)b*NCH + c)*DIN + d)*8 + n;
        Hinit[o] = h;
        h = PS[o] * h + PS[PSZ + o];
    }
}

// Pass C writes yg as bf16 (feeds out-proj MFMA GEMM)
__global__ __launch_bounds__(256) void scan_fin(const float* __restrict__ dt,
        const float* __restrict__ xc, const float* __restrict__ BC,
        const float* __restrict__ xz, const float* __restrict__ Alog,
        const float* __restrict__ Dp, const float* __restrict__ Hinit,
        unsigned short* __restrict__ yg)
{
    int b = blockIdx.x, c = blockIdx.y;
    int d = threadIdx.x;
    float a[NST], h[NST];
    long o = (((long)b*NCH + c)*DIN + d)*8;
    #pragma unroll
    for (int n = 0; n < NST; n++) { a[n] = -expf(Alog[d*NST + n]); h[n] = Hinit[o + n]; }
    float Dpd = Dp[d];
    int t0 = c*TCH;
    const float* dtp = dt + ((long)b*LL + t0)*DIN + d;
    const float* up  = xc + ((long)b*LL + t0)*DIN + d;
    const float* bc  = BC + ((long)b*LL + t0)*16;
    const float* zp  = xz + ((long)b*LL + t0)*512 + 256 + d;
    unsigned short* yo = yg + ((long)b*LL + t0)*DIN + d;
    for (int t = 0; t < TCH; t++) {
        float dtv = dtp[(long)t*DIN];
        float u   = up[(long)t*DIN];
        const float4* bc4 = (const float4*)(bc + t*16);
        float4 B0 = bc4[0], B1 = bc4[1], C0 = bc4[2], C1 = bc4[3];
        float Bv[NST] = {B0.x,B0.y,B0.z,B0.w,B1.x,B1.y,B1.z,B1.w};
        float Cv[NST] = {C0.x,C0.y,C0.z,C0.w,C1.x,C1.y,C1.z,C1.w};
        float dtu = dtv * u;
        float y = 0.f;
        #pragma unroll
        for (int n = 0; n < NST; n++) {
            float dA = __expf(dtv * a[n]);
            h[n] = dA * h[n] + dtu * Bv[n];
            y += h[n] * Cv[n];
        }
        y += u * Dpd;
        float z = zp[(long)t*512];
        yo[(long)t*DIN] = f2bf(y * siluf_(z));
    }
}

// ---------------- zero the 1-px border of padded [NP][P][P] planes ----------------
__global__ void zpad(float* __restrict__ buf, int NP, int P)
{
    int t = blockIdx.x*256 + threadIdx.x;
    int per = 4*P - 4;
    if (t >= NP*per) return;
    int pl = t / per, k = t % per;
    int r, c;
    if (k < P)        { r = 0;     c = k; }
    else if (k < 2*P) { r = P-1;   c = k - P; }
    else { int kk = k - 2*P; r = 1 + (kk >> 1); c = (kk & 1) ? (P-1) : 0; }
    buf[(long)pl*P*P + (long)r*P + c] = 0.f;
}

// ---------------- phase-decomposed up2+3x3 conv weights ----------------
__global__ void prep_weff(const float* __restrict__ Wr, float* __restrict__ We, int total)
{
    int t = blockIdx.x*256 + threadIdx.x;
    if (t >= total) return;
    float w[3][3];
    #pragma unroll
    for (int a = 0; a < 3; a++)
        #pragma unroll
        for (int c = 0; c < 3; c++) w[a][c] = Wr[(long)t*9 + a*3 + c];
    float cw[2][3][2];
    #pragma unroll
    for (int ky = 0; ky < 3; ky++) {
        cw[0][ky][0] = w[ky][0];           cw[0][ky][1] = w[ky][1] + w[ky][2];
        cw[1][ky][0] = w[ky][0] + w[ky][1]; cw[1][ky][1] = w[ky][2];
    }
    float* o = We + (long)t*16;   // [py][px][i*2+j]
    #pragma unroll
    for (int px = 0; px < 2; px++) {
        o[0*8+px*4+0] = cw[px][0][0];               o[0*8+px*4+1] = cw[px][0][1];
        o[0*8+px*4+2] = cw[px][1][0]+cw[px][2][0];  o[0*8+px*4+3] = cw[px][1][1]+cw[px][2][1];
        o[1*8+px*4+0] = cw[px][0][0]+cw[px][1][0];  o[1*8+px*4+1] = cw[px][0][1]+cw[px][1][1];
        o[1*8+px*4+2] = cw[px][2][0];               o[1*8+px*4+3] = cw[px][2][1];
    }
}

// Conv: ROWS=16, 512 threads, 2 oc/thread. Weights from LDS (r6 proven path);
// each b128 weight read now feeds 32 FMAs (2x r6) -> DS demand halved.
// Same per-output FMA expression / ic order as r6 -> bitwise-identical.
template<int CIN, int INW, int OPAD>
__global__ __launch_bounds__(512) void conv_up2_lw(const float* __restrict__ X,
        const float* __restrict__ We, const float* __restrict__ bias,
        const float* __restrict__ bng, const float* __restrict__ bnb,
        const float* __restrict__ bnm, const float* __restrict__ bnv,
        float* __restrict__ Y, int relu_first, int COUT)
{
    constexpr int OUTW = 2*INW;
    constexpr int NXT  = OUTW/64;
    constexpr int PW   = INW + 2;          // padded input width
    constexpr int OW   = OUTW + 2*OPAD;    // output stride
    constexpr int ICB  = 32;               // weight chunk
    __shared__ float wl[ICB][16][20];      // [icL][ocL][16 used, pad to 20] -> 40,960 B
    const int ys = blockIdx.x / NXT, xt = blockIdx.x % NXT;
    const int y0 = ys*16, x0 = xt*64;
    const int ocb = blockIdx.y * 16;
    const int b = blockIdx.z;
    const int tid = threadIdx.x;
    const int rel = tid & 63, ocq = tid >> 6;    // ocq 0..7, 2 oc each
    const int Xc = x0 + rel;
    const int px = Xc & 1;
    const int lcp = (rel >> 1) + px;
    float acc[16][2] = {};
    const float* sp = X + (long)(b*CIN)*(PW*PW) + (long)(y0>>1)*PW + (x0>>1) + lcp;
    for (int ic0 = 0; ic0 < CIN; ic0 += ICB) {
        __syncthreads();
        // stage weights: 16 oc x 32 ic x 4 float4 = 2048 float4s, 4 per thread
        for (int u = tid; u < 2048; u += 512) {
            int ocL = u >> 7, rem = u & 127;
            int icL = rem >> 2, k4 = rem & 3;
            *(float4*)&wl[icL][ocL][k4*4] =
                *(const float4*)&We[((long)(ocb+ocL)*CIN + ic0+icL)*16 + k4*4];
        }
        __syncthreads();
        for (int icL = 0; icL < ICB; icL++) {
            const float* q = sp + (long)(ic0+icL)*(PW*PW);
            float s[10][2];
            #pragma unroll
            for (int r = 0; r < 10; r++) { s[r][0] = q[r*PW]; s[r][1] = q[r*PW + 1]; }
            #pragma unroll
            for (int ol = 0; ol < 2; ol++) {
                float4 w0 = *(const float4*)&wl[icL][(ocq<<1)+ol][px*4];
                float4 w1 = *(const float4*)&wl[icL][(ocq<<1)+ol][8 + px*4];
                #pragma unroll
                for (int p = 0; p < 8; p++) {
                    acc[2*p  ][ol] += w0.x*s[p  ][0] + w0.y*s[p  ][1] + w0.z*s[p+1][0] + w0.w*s[p+1][1];
                    acc[2*p+1][ol] += w1.x*s[p+1][0] + w1.y*s[p+1][1] + w1.z*s[p+2][0] + w1.w*s[p+2][1];
                }
            }
        }
    }
    #pragma unroll
    for (int ol = 0; ol < 2; ol++) {
        int oc = ocb + (ocq<<1) + ol;
        float bi = bias[oc];
        float sc = bng[oc] * rsqrtf(bnv[oc] + 1e-5f);
        float sh = bnb[oc] - bnm[oc]*sc;
        #pragma unroll
        for (int yy = 0; yy < 16; yy++) {
            float v = acc[yy][ol] + bi;
            v = relu_first ? (fmaxf(v, 0.f)*sc + sh) : fmaxf(v*sc + sh, 0.f);
            Y[((long)(b*COUT + oc))*(OW*OW) + (long)(y0+yy+OPAD)*OW + (Xc+OPAD)] = v;
        }
    }
}

// ---------------- CCE gate partials (tiled matvec) ----------------
__global__ __launch_bounds__(256) void cce_gate_partial(const float* __restrict__ ox,
        const float* __restrict__ oy, const float* __restrict__ w1,
        float* __restrict__ pmax, float* __restrict__ psum)
{
    __shared__ float xs[32*512];
    __shared__ float wl[32*32];
    __shared__ float rmx[4][32], rsm[4][32];
    const int sg = blockIdx.x;
    const int dir = blockIdx.y, b = blockIdx.z;
    const float* X = (dir == 0 ? ox : oy) + (long)b*524288;
    const int t = threadIdx.x;
    for (int i = t; i < 1024; i += 256) { int oc = i >> 5, ic = i & 31; wl[ic*32 + oc] = w1[i]; }
    const int ocg = t & 3, pslot = t >> 2;
    const int oc0 = ocg*8;
    float mx[8], sm[8];
    #pragma unroll
    for (int j = 0; j < 8; j++) { mx[j] = -1e30f; sm[j] = 0.f; }
    const int base = sg*1024;
    for (int tile = 0; tile < 2; tile++) {
        __syncthreads();
        const int p0 = base + tile*512;
        for (int i = t*4; i < 32*512; i += 1024) {
            int ic = i >> 9, px = i & 511;
            *(float4*)&xs[ic*512 + px] = *(const float4*)&X[(long)ic*16384 + p0 + px];
        }
        __syncthreads();
        float acc[8][8];
        #pragma unroll
        for (int p = 0; p < 8; p++)
            #pragma unroll
            for (int j = 0; j < 8; j++) acc[p][j] = 0.f;
        #pragma unroll
        for (int ic = 0; ic < 32; ic++) {
            float4 x0 = *(const float4*)&xs[ic*512 + pslot*4];
            float4 x1 = *(const float4*)&xs[ic*512 + 256 + pslot*4];
            float4 wa = *(const float4*)&wl[ic*32 + oc0];
            float4 wb = *(const float4*)&wl[ic*32 + oc0 + 4];
            float xv[8] = {x0.x,x0.y,x0.z,x0.w,x1.x,x1.y,x1.z,x1.w};
            float wv[8] = {wa.x,wa.y,wa.z,wa.w,wb.x,wb.y,wb.z,wb.w};
            #pragma unroll
            for (int p = 0; p < 8; p++)
                #pragma unroll
                for (int j = 0; j < 8; j++)
                    acc[p][j] += xv[p]*wv[j];
        }
        #pragma unroll
        for (int p = 0; p < 8; p++)
            #pragma unroll
            for (int j = 0; j < 8; j++) { mx[j] = fmaxf(mx[j], acc[p][j]); sm[j] += acc[p][j]; }
    }
    #pragma unroll
    for (int j = 0; j < 8; j++) {
        #pragma unroll
        for (int off = 32; off >= 4; off >>= 1) {
            mx[j] = fmaxf(mx[j], __shfl_down(mx[j], off));
            sm[j] += __shfl_down(sm[j], off);
        }
    }
    const int wave = t >> 6, lane = t & 63;
    __syncthreads();
    if (lane < 4) {
        #pragma unroll
        for (int j = 0; j < 8; j++) { rmx[wave][lane*8+j] = mx[j]; rsm[wave][lane*8+j] = sm[j]; }
    }
    __syncthreads();
    if (t < 32) {
        float M = fmaxf(fmaxf(rmx[0][t], rmx[1][t]), fmaxf(rmx[2][t], rmx[3][t]));
        float S = rsm[0][t] + rsm[1][t] + rsm[2][t] + rsm[3][t];
        long idx = ((long)(dir*16 + b)*32 + t)*16 + sg;
        pmax[idx] = M; psum[idx] = S;
    }
}

__global__ void cce_gate_finish(const float* __restrict__ pmax, const float* __restrict__ psum,
                                float* __restrict__ gates)
{
    int i = blockIdx.x*64 + threadIdx.x;
    if (i < 1024) {
        float M = -1e30f, S = 0.f;
        #pragma unroll
        for (int sg = 0; sg < 16; sg++) { M = fmaxf(M, pmax[i*16+sg]); S += psum[i*16+sg]; }
        gates[i] = sigmoidf_(M + S*(1.f/16384.f));
    }
}

// ---------------- CCE add ----------------
__global__ __launch_bounds__(256) void cce_add(const float* __restrict__ ox,
        const float* __restrict__ oy, const float* __restrict__ w2,
        const float* __restrict__ gates, float* __restrict__ v)
{
    __shared__ float w[32][32];
    int t = threadIdx.x;
    int b = blockIdx.y;
    int s = blockIdx.x*256 + t;
    for (int i = t; i < 1024; i += 256) w[i>>5][i&31] = w2[i];
    __syncthreads();
    const float* xb = ox + (long)b*524288;
    const float* yb = oy + (long)b*524288;
    float r1[32] = {}, r2[32] = {};
    for (int ic = 0; ic < 32; ic++) {
        float xv = xb[(long)ic*16384 + s];
        float yv = yb[(long)ic*16384 + s];
        #pragma unroll
        for (int oc = 0; oc < 32; oc++) { r1[oc] += w[oc][ic]*yv; r2[oc] += w[oc][ic]*xv; }
    }
    float* vb = v + (long)b*524288;
    const float* g1 = gates + b*32;
    const float* g2 = gates + 512 + b*32;
    #pragma unroll
    for (int oc = 0; oc < 32; oc++)
        vb[(long)oc*16384 + s] += g1[oc]*r1[oc] + g2[oc]*r2[oc];
}

// ---------------- conv3 3x3 (32->1) + sigmoid ----------------
__global__ __launch_bounds__(256) void conv3_sig(const float* __restrict__ v,
        const float* __restrict__ w3, const float* __restrict__ b3, float* __restrict__ out)
{
    __shared__ float w[288];
    int t = threadIdx.x;
    for (int i = t; i < 288; i += 256) w[i] = w3[i];
    __syncthreads();
    int b = blockIdx.y;
    int y = blockIdx.x*2 + (t >> 7);
    int x = t & 127;
    const float* vb = v + (long)b*524288;
    float acc = b3[0];
    for (int ic = 0; ic < 32; ic++) {
        const float* p = vb + (long)ic*16384;
        #pragma unroll
        for (int ky = 0; ky < 3; ky++) {
            int yy = y + ky - 1;
            if ((unsigned)yy >= 128u) continue;
            #pragma unroll
            for (int kx = 0; kx < 3; kx++) {
                int xx = x + kx - 1;
                if ((unsigned)xx >= 128u) continue;
                acc += w[ic*9 + ky*3 + kx] * p[yy*128 + xx];
            }
        }
    }
    out[(long)b*16384 + y*128 + x] = sigmoidf_(acc);
}

// ---------------- launch ----------------
extern "C" void kernel_launch(void* const* d_in, const int* in_sizes, int n_in,
                              void* d_out, int out_size, void* d_ws, size_t ws_size,
                              hipStream_t stream)
{
    const float* fused_in = (const float*)d_in[0];
    const float* orig_x   = (const float*)d_in[1];
    const float* orig_y   = (const float*)d_in[2];
    const float* m_ln_g   = (const float*)d_in[3];
    const float* m_ln_b   = (const float*)d_in[4];
    const float* m_in_w   = (const float*)d_in[5];
    const float* m_conv_w = (const float*)d_in[6];
    const float* m_conv_b = (const float*)d_in[7];
    const float* m_xproj_w= (const float*)d_in[8];
    const float* m_dt_w   = (const float*)d_in[9];
    const float* m_dt_b   = (const float*)d_in[10];
    const float* m_Alog   = (const float*)d_in[11];
    const float* m_D      = (const float*)d_in[12];
    const float* m_out_w  = (const float*)d_in[13];
    const float* lnf_g    = (const float*)d_in[14];
    const float* lnf_b    = (const float*)d_in[15];
    const float* c1_w     = (const float*)d_in[16];
    const float* c1_b     = (const float*)d_in[17];
    const float* bn1_g    = (const float*)d_in[18];
    const float* bn1_b    = (const float*)d_in[19];
    const float* bn1_m    = (const float*)d_in[20];
    const float* bn1_v    = (const float*)d_in[21];
    const float* c2_w     = (const float*)d_in[22];
    const float* c2_b     = (const float*)d_in[23];
    const float* bn2_g    = (const float*)d_in[24];
    const float* bn2_b    = (const float*)d_in[25];
    const float* bn2_m    = (const float*)d_in[26];
    const float* bn2_v    = (const float*)d_in[27];
    const float* cce_w1   = (const float*)d_in[28];
    const float* cce_w2   = (const float*)d_in[29];
    const float* c3_w     = (const float*)d_in[30];
    const float* c3_b     = (const float*)d_in[31];

    float* W = (float*)d_ws;
    float* fusedA = W;                    // 2,097,152
    float* fusedB = W + 2097152;          // 2,097,152
    float* xzb    = W + 4194304;          // 8,388,608
    float* xcb    = W + 12582912;         // 4,194,304
    float* dtb    = W + 16777216;         // 4,194,304
    float* ygb    = W + 20971520;         // 4,194,304 (holds bf16 xln / bf16 yg / bf16 weights)
    float* BCb    = W + 25165824;         // 262,144
    float* gates  = W + 25427968;         // 1,024
    float* Hinit  = W + 25445376;         // 1,048,576
    float* pmax   = W + 26493952;         // 16,384
    float* psum   = W + 26510336;         // 16,384
    unsigned short* xlnb = (unsigned short*)ygb;   // 16384*128 bf16 (dead before yg written)
    unsigned short* ygbb = (unsigned short*)ygb;   // 16384*256 bf16
    unsigned short* wbf  = ((unsigned short*)ygb) + 4194304;  // bf16 GEMM weights
    // decoder buffers (xz region dead after last scan_fin/gemm of the loop):
    float* tb_pad  = xzb;                 // 16*128*34*34 = 2,367,488 floats (9.5 MB)
    float* c1b_pad = xzb + 2367488;       // 16*64*66*66  = 4,460,544 floats (17.8 MB)
    float* vb  = dtb;      // alias, spans dtb..ygb (8,388,608 floats)
    float* weff1 = BCb;             // 64*128*16 = 131072
    float* weff2 = BCb + 131072;    // 32*64*16  =  32768

    // CCE gates (independent of mamba chain)
    cce_gate_partial<<<dim3(16,2,16), 256, 0, stream>>>(orig_x, orig_y, cce_w1, pmax, psum);
    cce_gate_finish<<<16, 64, 0, stream>>>(pmax, psum, gates);

    // one-time f32->bf16 weight conversion for all 6 GEMMs
    wcvt<<<1152, 256, 0, stream>>>(m_in_w, m_out_w, wbf);

    const float* cur = fused_in;
    float* nxt = fusedA;
    for (int i = 0; i < 3; i++) {
        ln_bf16_kernel<<<NROWS, 64, 0, stream>>>(cur, m_ln_g + i*128, m_ln_b + i*128, xlnb);
        gemm_bf16<128,128><<<dim3(128, 4), 256, 0, stream>>>(xlnb, wbf + (long)i*65536, nullptr, xzb, 512);
        dwconv_xproj<<<NROWS, 256, 0, stream>>>(xzb, m_conv_w + i*1024, m_conv_b + i*256,
                m_xproj_w + i*24*256, m_dt_w + i*2048, m_dt_b + i*256, xcb, dtb, BCb);
        scan_part<<<dim3(BB, NCH), 256, 0, stream>>>(dtb, xcb, BCb, m_Alog + i*2048, nxt);
        scan_mid<<<dim3(BB, NST), 256, 0, stream>>>(nxt, Hinit);
        scan_fin<<<dim3(BB, NCH), 256, 0, stream>>>(dtb, xcb, BCb, xzb, m_Alog + i*2048, m_D + i*256, Hinit, ygbb);
        gemm_bf16<256,64><<<dim3(256, 1), 256, 0, stream>>>(ygbb, wbf + 196608 + (long)i*32768, cur, nxt, 128);
        cur = nxt;
        nxt = (i == 0) ? fusedB : fusedA;
    }
    // cur == fusedA here (A -> B -> A). xz region now dead -> decoder buffers.
    zpad<<<1056, 256, 0, stream>>>(tb_pad, 2048, 34);     // 16*128 planes
    zpad<<<1040, 256, 0, stream>>>(c1b_pad, 1024, 66);    // 16*64 planes
    ln_kernel<<<NROWS, 64, 0, stream>>>(cur, lnf_g, lnf_b, tb_pad, 1);
    prep_weff<<<32, 256, 0, stream>>>(c1_w, weff1, 64*128);
    prep_weff<<<8, 256, 0, stream>>>(c2_w, weff2, 32*64);
    // ROWS=16, 512-thread blocks: conv1 4*4*16 = 256 blocks (1/CU, 8 waves);
    // conv2 16*2*16 = 512 blocks (2/CU, 16 waves)
    conv_up2_lw<128, 32, 1><<<dim3(4, 4, 16), 512, 0, stream>>>(tb_pad, weff1, c1_b, bn1_g, bn1_b, bn1_m, bn1_v, c1b_pad, 0, 64);
    conv_up2_lw<64, 64, 0><<<dim3(16, 2, 16), 512, 0, stream>>>(c1b_pad, weff2, c2_b, bn2_g, bn2_b, bn2_m, bn2_v, vb, 1, 32);
    cce_add<<<dim3(64, 16), 256, 0, stream>>>(orig_x, orig_y, cce_w2, gates, vb);
    conv3_sig<<<dim3(64, 16), 256, 0, stream>>>(vb, c3_w, c3_b, (float*)d_out);
}

// Round 8
// 788.253 us; speedup vs baseline: 1.1166x; 1.1166x over previous
//
#include <hip/hip_runtime.h>
#include <hip/hip_bf16.h>

// ---------------- sizes ----------------
#define BB   16
#define LL   1024
#define DM   128
#define DIN  256
#define NST  8
#define NROWS (BB*LL)      // 16384
#define NCH  32
#define TCH  32
#define PSZ  1048576       // B*NCH*DIN*8

static __device__ __forceinline__ float sigmoidf_(float x){ return 1.f/(1.f+expf(-x)); }
static __device__ __forceinline__ float siluf_(float x){ return x/(1.f+expf(-x)); }
static __device__ __forceinline__ unsigned short f2bf(float f){
    union { float f; unsigned u; } v; v.f = f;
    unsigned r = v.u + 0x7fff + ((v.u >> 16) & 1);
    return (unsigned short)(r >> 16);
}

typedef __attribute__((ext_vector_type(8))) short short8;
typedef __attribute__((ext_vector_type(4))) float floatx4;

// ---------------- LayerNorm -> f32 (PADDED transpose for decoder conv1) ----------------
__global__ __launch_bounds__(64) void ln_kernel(const float* __restrict__ X,
        const float* __restrict__ g, const float* __restrict__ b,
        float* __restrict__ Y, int transpose)
{
    int row = blockIdx.x;
    int t = threadIdx.x;
    float x0 = X[(long)row*DM + t];
    float x1 = X[(long)row*DM + 64 + t];
    float s = x0 + x1, ss = x0*x0 + x1*x1;
    #pragma unroll
    for (int off = 32; off; off >>= 1) { s += __shfl_down(s, off); ss += __shfl_down(ss, off); }
    s = __shfl(s, 0); ss = __shfl(ss, 0);
    float mean = s * (1.f/128.f);
    float var  = ss * (1.f/128.f) - mean*mean;
    float inv  = rsqrtf(var + 1e-5f);
    float y0 = (x0-mean)*inv*g[t]    + b[t];
    float y1 = (x1-mean)*inv*g[64+t] + b[64+t];
    if (!transpose) {
        Y[(long)row*DM + t] = y0;
        Y[(long)row*DM + 64 + t] = y1;
    } else {
        int bb = row >> 10, l = row & 1023;
        int r = l >> 5, c = l & 31;
        Y[((long)(bb*DM + t)*34 + (r+1))*34 + (c+1)]      = y0;
        Y[((long)(bb*DM + 64 + t)*34 + (r+1))*34 + (c+1)] = y1;
    }
}

// ---------------- LayerNorm -> bf16 (feeds MFMA GEMM) ----------------
__global__ __launch_bounds__(64) void ln_bf16_kernel(const float* __restrict__ X,
        const float* __restrict__ g, const float* __restrict__ b,
        unsigned short* __restrict__ Y)
{
    int row = blockIdx.x;
    int t = threadIdx.x;
    float x0 = X[(long)row*DM + t];
    float x1 = X[(long)row*DM + 64 + t];
    float s = x0 + x1, ss = x0*x0 + x1*x1;
    #pragma unroll
    for (int off = 32; off; off >>= 1) { s += __shfl_down(s, off); ss += __shfl_down(ss, off); }
    s = __shfl(s, 0); ss = __shfl(ss, 0);
    float mean = s * (1.f/128.f);
    float var  = ss * (1.f/128.f) - mean*mean;
    float inv  = rsqrtf(var + 1e-5f);
    Y[(long)row*DM + t]      = f2bf((x0-mean)*inv*g[t]    + b[t]);
    Y[(long)row*DM + 64 + t] = f2bf((x1-mean)*inv*g[64+t] + b[64+t]);
}

// ---------------- one-time weight f32->bf16 conversion ----------------
__global__ void wcvt(const float* __restrict__ Win, const float* __restrict__ Wout,
                     unsigned short* __restrict__ Wb)
{
    int t = blockIdx.x*256 + threadIdx.x;
    if (t < 196608) Wb[t] = f2bf(Win[t]);
    else if (t < 294912) Wb[t] = f2bf(Wout[t - 196608]);
}

// ---------------- bf16-MFMA GEMM: C[M,N] = A[M,K](bf16) @ W[N,K]^T(bf16) (+S) ----------------
template<int K, int MT>
__global__ __launch_bounds__(256) void gemm_bf16(const unsigned short* __restrict__ A,
        const unsigned short* __restrict__ Wb, const float* __restrict__ S,
        float* __restrict__ C, int N)
{
    constexpr int NMT = MT/64;
    __shared__ unsigned short Als[MT][40];
    __shared__ unsigned short Bls[128][40];
    const int tid = threadIdx.x;
    const int m0 = blockIdx.x * MT;
    const int n0 = blockIdx.y * 128;
    const int lane = tid & 63, wv = tid >> 6;
    const int fr = lane & 15, quad = lane >> 4;
    floatx4 acc[NMT][8];
    #pragma unroll
    for (int mt = 0; mt < NMT; mt++)
        #pragma unroll
        for (int nt = 0; nt < 8; nt++) acc[mt][nt] = (floatx4){0.f,0.f,0.f,0.f};
    for (int kc = 0; kc < K; kc += 32) {
        __syncthreads();
        #pragma unroll
        for (int u = tid; u < MT*4; u += 256) {          // A: bf16 16B vector copy
            int row = u >> 2, seg = u & 3;
            *(uint4*)&Als[row][seg*8] = *(const uint4*)&A[(long)(m0+row)*K + kc + seg*8];
        }
        #pragma unroll
        for (int u = tid; u < 512; u += 256) {           // W: bf16 16B vector copy
            int row = u >> 2, seg = u & 3;
            *(uint4*)&Bls[row][seg*8] = *(const uint4*)&Wb[(long)(n0+row)*K + kc + seg*8];
        }
        __syncthreads();
        short8 af[NMT];
        #pragma unroll
        for (int mt = 0; mt < NMT; mt++)
            af[mt] = *(const short8*)&Als[wv*(16*NMT) + mt*16 + fr][quad*8];
        #pragma unroll
        for (int nt = 0; nt < 8; nt++) {
            short8 bfv = *(const short8*)&Bls[nt*16 + fr][quad*8];
            #pragma unroll
            for (int mt = 0; mt < NMT; mt++)
                acc[mt][nt] = __builtin_amdgcn_mfma_f32_16x16x32_bf16(af[mt], bfv, acc[mt][nt], 0, 0, 0);
        }
    }
    const int rq = quad * 4;
    #pragma unroll
    for (int mt = 0; mt < NMT; mt++)
        #pragma unroll
        for (int nt = 0; nt < 8; nt++)
            #pragma unroll
            for (int r = 0; r < 4; r++) {
                long m = m0 + wv*(16*NMT) + mt*16 + rq + r;
                long n = n0 + nt*16 + fr;
                float v = acc[mt][nt][r];
                if (S) v += S[m*N + n];
                C[m*N + n] = v;
            }
}

// ---------------- fused depthwise conv+SiLU and x-proj/dt-proj/softplus ----------------
// L-tiled: 8 consecutive l per block (2048 blocks). xz taps staged in LDS once;
// xproj_w / dt_w words read once per 8 l (8x global-weight-traffic cut).
// All accumulation orders identical to the per-l version -> bitwise-identical.
#define LT 8
__global__ __launch_bounds__(256) void dwconv_xproj(const float* __restrict__ xz,
        const float* __restrict__ cw, const float* __restrict__ cb,
        const float* __restrict__ xproj_w, const float* __restrict__ dt_w,
        const float* __restrict__ dt_b, float* __restrict__ xc,
        float* __restrict__ dt_out, float* __restrict__ BC)
{
    __shared__ float xstage[LT+3][DIN];   // rows l0-3 .. l0+7
    __shared__ float xs2[LT][DIN];
    __shared__ float xdbl2[LT][24];
    const int idx = blockIdx.x;
    const int b = idx >> 7;
    const int l0 = (idx & 127) * LT;
    const int d = threadIdx.x;
    // stage xz x-half rows [l0-3, l0+7]
    for (int i = d; i < (LT+3)*DIN; i += 256) {
        int row = i >> 8, dd = i & 255;
        int gl = l0 - 3 + row;
        xstage[row][dd] = (gl >= 0) ? xz[((long)b*LL + gl)*512 + dd] : 0.f;
    }
    float w0 = cw[d*4+0], w1 = cw[d*4+1], w2 = cw[d*4+2], w3 = cw[d*4+3];
    float cbd = cb[d];
    __syncthreads();
    #pragma unroll
    for (int lt = 0; lt < LT; lt++) {
        int l = l0 + lt;
        float acc = cbd + w3 * xstage[lt+3][d];
        if (l >= 1) acc += w2 * xstage[lt+2][d];
        if (l >= 2) acc += w1 * xstage[lt+1][d];
        if (l >= 3) acc += w0 * xstage[lt][d];
        float u = siluf_(acc);
        xs2[lt][d] = u;
        xc[((long)b*LL + l)*DIN + d] = u;
    }
    __syncthreads();
    int t = d;
    if (t < 192) {                       // 24 outputs x 8 lanes, 8 l each
        int e = t >> 3, j = t & 7;
        float p[LT];
        #pragma unroll
        for (int lt = 0; lt < LT; lt++) p[lt] = 0.f;
        for (int k = j; k < DIN; k += 8) {
            float w = xproj_w[e*DIN + k];
            #pragma unroll
            for (int lt = 0; lt < LT; lt++) p[lt] += xs2[lt][k] * w;
        }
        #pragma unroll
        for (int lt = 0; lt < LT; lt++) {
            p[lt] += __shfl_down(p[lt], 4, 8);
            p[lt] += __shfl_down(p[lt], 2, 8);
            p[lt] += __shfl_down(p[lt], 1, 8);
        }
        if (j == 0) {
            #pragma unroll
            for (int lt = 0; lt < LT; lt++) xdbl2[lt][e] = p[lt];
        }
    }
    __syncthreads();
    float dw[8];
    #pragma unroll
    for (int r = 0; r < 8; r++) dw[r] = dt_w[d*8 + r];
    float dtbd = dt_b[d];
    #pragma unroll
    for (int lt = 0; lt < LT; lt++) {
        float v = dtbd;
        #pragma unroll
        for (int r = 0; r < 8; r++) v += xdbl2[lt][r] * dw[r];
        v = (v > 20.f) ? v : log1pf(expf(v));           // softplus
        dt_out[((long)b*LL + l0 + lt)*DIN + d] = v;
    }
    if (t < 128) {
        int lt = t >> 4, j = t & 15;
        BC[((long)b*LL + l0 + lt)*16 + j] = xdbl2[lt][8 + j];
    }
}

// ---------------- chunked selective scan ----------------
__global__ __launch_bounds__(256) void scan_part(const float* __restrict__ dt,
        const float* __restrict__ xc, const float* __restrict__ BC,
        const float* __restrict__ Alog, float* __restrict__ PS)
{
    int b = blockIdx.x, c = blockIdx.y;
    int d = threadIdx.x;
    float a[NST], P[NST], S[NST];
    #pragma unroll
    for (int n = 0; n < NST; n++) { a[n] = -expf(Alog[d*NST + n]); P[n] = 1.f; S[n] = 0.f; }
    int t0 = c*TCH;
    const float* dtp = dt + ((long)b*LL + t0)*DIN + d;
    const float* up  = xc + ((long)b*LL + t0)*DIN + d;
    const float* bc  = BC + ((long)b*LL + t0)*16;
    for (int t = 0; t < TCH; t++) {
        float dtv = dtp[(long)t*DIN];
        float u   = up[(long)t*DIN];
        const float4* bc4 = (const float4*)(bc + t*16);
        float4 B0 = bc4[0], B1 = bc4[1];
        float Bv[NST] = {B0.x,B0.y,B0.z,B0.w,B1.x,B1.y,B1.z,B1.w};
        float dtu = dtv * u;
        #pragma unroll
        for (int n = 0; n < NST; n++) {
            float dA = __expf(dtv * a[n]);
            S[n] = dA * S[n] + dtu * Bv[n];
            P[n] *= dA;
        }
    }
    long o = (((long)b*NCH + c)*DIN + d)*8;
    #pragma unroll
    for (int n = 0; n < NST; n++) { PS[o + n] = P[n]; PS[PSZ + o + n] = S[n]; }
}

// parallelized over (b, n): 128 blocks, one (b,d,n) recurrence per thread.
__global__ __launch_bounds__(256) void scan_mid(const float* __restrict__ PS,
        float* __restrict__ Hinit)
{
    int b = blockIdx.x;
    int n = blockIdx.y;
    int d = threadIdx.x;
    float h = 0.f;
    for (int c = 0; c < NCH; c++) {
        long o = (((long)b*NCH + c)*DIN + d)*8 + n;
        Hinit[o] = h;
        h = PS[o] * h + PS[PSZ + o];
    }
}

// Pass C writes yg as bf16 (feeds out-proj MFMA GEMM)
__global__ __launch_bounds__(256) void scan_fin(const float* __restrict__ dt,
        const float* __restrict__ xc, const float* __restrict__ BC,
        const float* __restrict__ xz, const float* __restrict__ Alog,
        const float* __restrict__ Dp, const float* __restrict__ Hinit,
        unsigned short* __restrict__ yg)
{
    int b = blockIdx.x, c = blockIdx.y;
    int d = threadIdx.x;
    float a[NST], h[NST];
    long o = (((long)b*NCH + c)*DIN + d)*8;
    #pragma unroll
    for (int n = 0; n < NST; n++) { a[n] = -expf(Alog[d*NST + n]); h[n] = Hinit[o + n]; }
    float Dpd = Dp[d];
    int t0 = c*TCH;
    const float* dtp = dt + ((long)b*LL + t0)*DIN + d;
    const float* up  = xc + ((long)b*LL + t0)*DIN + d;
    const float* bc  = BC + ((long)b*LL + t0)*16;
    const float* zp  = xz + ((long)b*LL + t0)*512 + 256 + d;
    unsigned short* yo = yg + ((long)b*LL + t0)*DIN + d;
    for (int t = 0; t < TCH; t++) {
        float dtv = dtp[(long)t*DIN];
        float u   = up[(long)t*DIN];
        const float4* bc4 = (const float4*)(bc + t*16);
        float4 B0 = bc4[0], B1 = bc4[1], C0 = bc4[2], C1 = bc4[3];
        float Bv[NST] = {B0.x,B0.y,B0.z,B0.w,B1.x,B1.y,B1.z,B1.w};
        float Cv[NST] = {C0.x,C0.y,C0.z,C0.w,C1.x,C1.y,C1.z,C1.w};
        float dtu = dtv * u;
        float y = 0.f;
        #pragma unroll
        for (int n = 0; n < NST; n++) {
            float dA = __expf(dtv * a[n]);
            h[n] = dA * h[n] + dtu * Bv[n];
            y += h[n] * Cv[n];
        }
        y += u * Dpd;
        float z = zp[(long)t*512];
        yo[(long)t*DIN] = f2bf(y * siluf_(z));
    }
}

// ---------------- zero the 1-px border of padded [NP][P][P] planes ----------------
__global__ void zpad(float* __restrict__ buf, int NP, int P)
{
    int t = blockIdx.x*256 + threadIdx.x;
    int per = 4*P - 4;
    if (t >= NP*per) return;
    int pl = t / per, k = t % per;
    int r, c;
    if (k < P)        { r = 0;     c = k; }
    else if (k < 2*P) { r = P-1;   c = k - P; }
    else { int kk = k - 2*P; r = 1 + (kk >> 1); c = (kk & 1) ? (P-1) : 0; }
    buf[(long)pl*P*P + (long)r*P + c] = 0.f;
}

// ---------------- phase-decomposed up2+3x3 conv weights ----------------
__global__ void prep_weff(const float* __restrict__ Wr, float* __restrict__ We, int total)
{
    int t = blockIdx.x*256 + threadIdx.x;
    if (t >= total) return;
    float w[3][3];
    #pragma unroll
    for (int a = 0; a < 3; a++)
        #pragma unroll
        for (int c = 0; c < 3; c++) w[a][c] = Wr[(long)t*9 + a*3 + c];
    float cw[2][3][2];
    #pragma unroll
    for (int ky = 0; ky < 3; ky++) {
        cw[0][ky][0] = w[ky][0];           cw[0][ky][1] = w[ky][1] + w[ky][2];
        cw[1][ky][0] = w[ky][0] + w[ky][1]; cw[1][ky][1] = w[ky][2];
    }
    float* o = We + (long)t*16;   // [py][px][i*2+j]
    #pragma unroll
    for (int px = 0; px < 2; px++) {
        o[0*8+px*4+0] = cw[px][0][0];               o[0*8+px*4+1] = cw[px][0][1];
        o[0*8+px*4+2] = cw[px][1][0]+cw[px][2][0];  o[0*8+px*4+3] = cw[px][1][1]+cw[px][2][1];
        o[1*8+px*4+0] = cw[px][0][0]+cw[px][1][0];  o[1*8+px*4+1] = cw[px][0][1]+cw[px][1][1];
        o[1*8+px*4+2] = cw[px][2][0];               o[1*8+px*4+3] = cw[px][2][1];
    }
}

// Conv (round-6 proven version): src direct from padded global, weights from LDS.
template<int CIN, int INW, int OPAD>
__global__ __launch_bounds__(256) void conv_up2_lw(const float* __restrict__ X,
        const float* __restrict__ We, const float* __restrict__ bias,
        const float* __restrict__ bng, const float* __restrict__ bnb,
        const float* __restrict__ bnm, const float* __restrict__ bnv,
        float* __restrict__ Y, int relu_first, int COUT)
{
    constexpr int OUTW = 2*INW;
    constexpr int NXT  = OUTW/64;
    constexpr int PW   = INW + 2;          // padded input width
    constexpr int OW   = OUTW + 2*OPAD;    // output stride
    constexpr int ICB  = 32;               // weight chunk
    __shared__ float wl[ICB][16][20];      // [icL][ocL][16 used, pad to 20] -> 40,960 B
    const int ys = blockIdx.x / NXT, xt = blockIdx.x % NXT;
    const int y0 = ys*8, x0 = xt*64;
    const int ocb = blockIdx.y * 16;
    const int b = blockIdx.z;
    const int tid = threadIdx.x;
    const int rel = tid & 63, ocq = tid >> 6;
    const int Xc = x0 + rel;
    const int px = Xc & 1;
    const int lcp = (rel >> 1) + px;
    float acc[8][4] = {};
    const float* sp = X + (long)(b*CIN)*(PW*PW) + (long)(y0>>1)*PW + (x0>>1) + lcp;
    for (int ic0 = 0; ic0 < CIN; ic0 += ICB) {
        __syncthreads();
        // stage weights: 16 oc x 32 ic x 4 float4 = 2048 float4s, 8 per thread
        for (int u = tid; u < 2048; u += 256) {
            int ocL = u >> 7, rem = u & 127;
            int icL = rem >> 2, k4 = rem & 3;
            *(float4*)&wl[icL][ocL][k4*4] =
                *(const float4*)&We[((long)(ocb+ocL)*CIN + ic0+icL)*16 + k4*4];
        }
        __syncthreads();
        for (int icL = 0; icL < ICB; icL++) {
            const float* q = sp + (long)(ic0+icL)*(PW*PW);
            float s[6][2];
            #pragma unroll
            for (int r = 0; r < 6; r++) { s[r][0] = q[r*PW]; s[r][1] = q[r*PW + 1]; }
            #pragma unroll
            for (int ol = 0; ol < 4; ol++) {
                float4 w0 = *(const float4*)&wl[icL][(ocq<<2)+ol][px*4];
                float4 w1 = *(const float4*)&wl[icL][(ocq<<2)+ol][8 + px*4];
                #pragma unroll
                for (int p = 0; p < 4; p++) {
                    acc[2*p  ][ol] += w0.x*s[p  ][0] + w0.y*s[p  ][1] + w0.z*s[p+1][0] + w0.w*s[p+1][1];
                    acc[2*p+1][ol] += w1.x*s[p+1][0] + w1.y*s[p+1][1] + w1.z*s[p+2][0] + w1.w*s[p+2][1];
                }
            }
        }
    }
    #pragma unroll
    for (int ol = 0; ol < 4; ol++) {
        int oc = ocb + (ocq<<2) + ol;
        float bi = bias[oc];
        float sc = bng[oc] * rsqrtf(bnv[oc] + 1e-5f);
        float sh = bnb[oc] - bnm[oc]*sc;
        #pragma unroll
        for (int yy = 0; yy < 8; yy++) {
            float v = acc[yy][ol] + bi;
            v = relu_first ? (fmaxf(v, 0.f)*sc + sh) : fmaxf(v*sc + sh, 0.f);
            Y[((long)(b*COUT + oc))*(OW*OW) + (long)(y0+yy+OPAD)*OW + (Xc+OPAD)] = v;
        }
    }
}

// ---------------- CCE gate partials (tiled matvec) ----------------
__global__ __launch_bounds__(256) void cce_gate_partial(const float* __restrict__ ox,
        const float* __restrict__ oy, const float* __restrict__ w1,
        float* __restrict__ pmax, float* __restrict__ psum)
{
    __shared__ float xs[32*512];
    __shared__ float wl[32*32];
    __shared__ float rmx[4][32], rsm[4][32];
    const int sg = blockIdx.x;
    const int dir = blockIdx.y, b = blockIdx.z;
    const float* X = (dir == 0 ? ox : oy) + (long)b*524288;
    const int t = threadIdx.x;
    for (int i = t; i < 1024; i += 256) { int oc = i >> 5, ic = i & 31; wl[ic*32 + oc] = w1[i]; }
    const int ocg = t & 3, pslot = t >> 2;
    const int oc0 = ocg*8;
    float mx[8], sm[8];
    #pragma unroll
    for (int j = 0; j < 8; j++) { mx[j] = -1e30f; sm[j] = 0.f; }
    const int base = sg*1024;
    for (int tile = 0; tile < 2; tile++) {
        __syncthreads();
        const int p0 = base + tile*512;
        for (int i = t*4; i < 32*512; i += 1024) {
            int ic = i >> 9, px = i & 511;
            *(float4*)&xs[ic*512 + px] = *(const float4*)&X[(long)ic*16384 + p0 + px];
        }
        __syncthreads();
        float acc[8][8];
        #pragma unroll
        for (int p = 0; p < 8; p++)
            #pragma unroll
            for (int j = 0; j < 8; j++) acc[p][j] = 0.f;
        #pragma unroll
        for (int ic = 0; ic < 32; ic++) {
            float4 x0 = *(const float4*)&xs[ic*512 + pslot*4];
            float4 x1 = *(const float4*)&xs[ic*512 + 256 + pslot*4];
            float4 wa = *(const float4*)&wl[ic*32 + oc0];
            float4 wb = *(const float4*)&wl[ic*32 + oc0 + 4];
            float xv[8] = {x0.x,x0.y,x0.z,x0.w,x1.x,x1.y,x1.z,x1.w};
            float wv[8] = {wa.x,wa.y,wa.z,wa.w,wb.x,wb.y,wb.z,wb.w};
            #pragma unroll
            for (int p = 0; p < 8; p++)
                #pragma unroll
                for (int j = 0; j < 8; j++)
                    acc[p][j] += xv[p]*wv[j];
        }
        #pragma unroll
        for (int p = 0; p < 8; p++)
            #pragma unroll
            for (int j = 0; j < 8; j++) { mx[j] = fmaxf(mx[j], acc[p][j]); sm[j] += acc[p][j]; }
    }
    #pragma unroll
    for (int j = 0; j < 8; j++) {
        #pragma unroll
        for (int off = 32; off >= 4; off >>= 1) {
            mx[j] = fmaxf(mx[j], __shfl_down(mx[j], off));
            sm[j] += __shfl_down(sm[j], off);
        }
    }
    const int wave = t >> 6, lane = t & 63;
    __syncthreads();
    if (lane < 4) {
        #pragma unroll
        for (int j = 0; j < 8; j++) { rmx[wave][lane*8+j] = mx[j]; rsm[wave][lane*8+j] = sm[j]; }
    }
    __syncthreads();
    if (t < 32) {
        float M = fmaxf(fmaxf(rmx[0][t], rmx[1][t]), fmaxf(rmx[2][t], rmx[3][t]));
        float S = rsm[0][t] + rsm[1][t] + rsm[2][t] + rsm[3][t];
        long idx = ((long)(dir*16 + b)*32 + t)*16 + sg;
        pmax[idx] = M; psum[idx] = S;
    }
}

__global__ void cce_gate_finish(const float* __restrict__ pmax, const float* __restrict__ psum,
                                float* __restrict__ gates)
{
    int i = blockIdx.x*64 + threadIdx.x;
    if (i < 1024) {
        float M = -1e30f, S = 0.f;
        #pragma unroll
        for (int sg = 0; sg < 16; sg++) { M = fmaxf(M, pmax[i*16+sg]); S += psum[i*16+sg]; }
        gates[i] = sigmoidf_(M + S*(1.f/16384.f));
    }
}

// ---------------- CCE add ----------------
__global__ __launch_bounds__(256) void cce_add(const float* __restrict__ ox,
        const float* __restrict__ oy, const float* __restrict__ w2,
        const float* __restrict__ gates, float* __restrict__ v)
{
    __shared__ float w[32][32];
    int t = threadIdx.x;
    int b = blockIdx.y;
    int s = blockIdx.x*256 + t;
    for (int i = t; i < 1024; i += 256) w[i>>5][i&31] = w2[i];
    __syncthreads();
    const float* xb = ox + (long)b*524288;
    const float* yb = oy + (long)b*524288;
    float r1[32] = {}, r2[32] = {};
    for (int ic = 0; ic < 32; ic++) {
        float xv = xb[(long)ic*16384 + s];
        float yv = yb[(long)ic*16384 + s];
        #pragma unroll
        for (int oc = 0; oc < 32; oc++) { r1[oc] += w[oc][ic]*yv; r2[oc] += w[oc][ic]*xv; }
    }
    float* vb = v + (long)b*524288;
    const float* g1 = gates + b*32;
    const float* g2 = gates + 512 + b*32;
    #pragma unroll
    for (int oc = 0; oc < 32; oc++)
        vb[(long)oc*16384 + s] += g1[oc]*r1[oc] + g2[oc]*r2[oc];
}

// ---------------- conv3 3x3 (32->1) + sigmoid ----------------
__global__ __launch_bounds__(256) void conv3_sig(const float* __restrict__ v,
        const float* __restrict__ w3, const float* __restrict__ b3, float* __restrict__ out)
{
    __shared__ float w[288];
    int t = threadIdx.x;
    for (int i = t; i < 288; i += 256) w[i] = w3[i];
    __syncthreads();
    int b = blockIdx.y;
    int y = blockIdx.x*2 + (t >> 7);
    int x = t & 127;
    const float* vb = v + (long)b*524288;
    float acc = b3[0];
    for (int ic = 0; ic < 32; ic++) {
        const float* p = vb + (long)ic*16384;
        #pragma unroll
        for (int ky = 0; ky < 3; ky++) {
            int yy = y + ky - 1;
            if ((unsigned)yy >= 128u) continue;
            #pragma unroll
            for (int kx = 0; kx < 3; kx++) {
                int xx = x + kx - 1;
                if ((unsigned)xx >= 128u) continue;
                acc += w[ic*9 + ky*3 + kx] * p[yy*128 + xx];
            }
        }
    }
    out[(long)b*16384 + y*128 + x] = sigmoidf_(acc);
}

// ---------------- launch ----------------
extern "C" void kernel_launch(void* const* d_in, const int* in_sizes, int n_in,
                              void* d_out, int out_size, void* d_ws, size_t ws_size,
                              hipStream_t stream)
{
    const float* fused_in = (const float*)d_in[0];
    const float* orig_x   = (const float*)d_in[1];
    const float* orig_y   = (const float*)d_in[2];
    const float* m_ln_g   = (const float*)d_in[3];
    const float* m_ln_b   = (const float*)d_in[4];
    const float* m_in_w   = (const float*)d_in[5];
    const float* m_conv_w = (const float*)d_in[6];
    const float* m_conv_b = (const float*)d_in[7];
    const float* m_xproj_w= (const float*)d_in[8];
    const float* m_dt_w   = (const float*)d_in[9];
    const float* m_dt_b   = (const float*)d_in[10];
    const float* m_Alog   = (const float*)d_in[11];
    const float* m_D      = (const float*)d_in[12];
    const float* m_out_w  = (const float*)d_in[13];
    const float* lnf_g    = (const float*)d_in[14];
    const float* lnf_b    = (const float*)d_in[15];
    const float* c1_w     = (const float*)d_in[16];
    const float* c1_b     = (const float*)d_in[17];
    const float* bn1_g    = (const float*)d_in[18];
    const float* bn1_b    = (const float*)d_in[19];
    const float* bn1_m    = (const float*)d_in[20];
    const float* bn1_v    = (const float*)d_in[21];
    const float* c2_w     = (const float*)d_in[22];
    const float* c2_b     = (const float*)d_in[23];
    const float* bn2_g    = (const float*)d_in[24];
    const float* bn2_b    = (const float*)d_in[25];
    const float* bn2_m    = (const float*)d_in[26];
    const float* bn2_v    = (const float*)d_in[27];
    const float* cce_w1   = (const float*)d_in[28];
    const float* cce_w2   = (const float*)d_in[29];
    const float* c3_w     = (const float*)d_in[30];
    const float* c3_b     = (const float*)d_in[31];

    float* W = (float*)d_ws;
    float* fusedA = W;                    // 2,097,152
    float* fusedB = W + 2097152;          // 2,097,152
    float* xzb    = W + 4194304;          // 8,388,608
    float* xcb    = W + 12582912;         // 4,194,304
    float* dtb    = W + 16777216;         // 4,194,304
    float* ygb    = W + 20971520;         // 4,194,304 (holds bf16 xln / bf16 yg / bf16 weights)
    float* BCb    = W + 25165824;         // 262,144
    float* gates  = W + 25427968;         // 1,024
    float* Hinit  = W + 25445376;         // 1,048,576
    float* pmax   = W + 26493952;         // 16,384
    float* psum   = W + 26510336;         // 16,384
    unsigned short* xlnb = (unsigned short*)ygb;   // 16384*128 bf16 (dead before yg written)
    unsigned short* ygbb = (unsigned short*)ygb;   // 16384*256 bf16
    unsigned short* wbf  = ((unsigned short*)ygb) + 4194304;  // bf16 GEMM weights
    // decoder buffers (xz region dead after last scan_fin/gemm of the loop):
    float* tb_pad  = xzb;                 // 16*128*34*34 = 2,367,488 floats (9.5 MB)
    float* c1b_pad = xzb + 2367488;       // 16*64*66*66  = 4,460,544 floats (17.8 MB)
    float* vb  = dtb;      // alias, spans dtb..ygb (8,388,608 floats)
    float* weff1 = BCb;             // 64*128*16 = 131072
    float* weff2 = BCb + 131072;    // 32*64*16  =  32768

    // CCE gates (independent of mamba chain)
    cce_gate_partial<<<dim3(16,2,16), 256, 0, stream>>>(orig_x, orig_y, cce_w1, pmax, psum);
    cce_gate_finish<<<16, 64, 0, stream>>>(pmax, psum, gates);

    // one-time f32->bf16 weight conversion for all 6 GEMMs
    wcvt<<<1152, 256, 0, stream>>>(m_in_w, m_out_w, wbf);

    const float* cur = fused_in;
    float* nxt = fusedA;
    for (int i = 0; i < 3; i++) {
        ln_bf16_kernel<<<NROWS, 64, 0, stream>>>(cur, m_ln_g + i*128, m_ln_b + i*128, xlnb);
        gemm_bf16<128,128><<<dim3(128, 4), 256, 0, stream>>>(xlnb, wbf + (long)i*65536, nullptr, xzb, 512);
        dwconv_xproj<<<2048, 256, 0, stream>>>(xzb, m_conv_w + i*1024, m_conv_b + i*256,
                m_xproj_w + i*24*256, m_dt_w + i*2048, m_dt_b + i*256, xcb, dtb, BCb);
        scan_part<<<dim3(BB, NCH), 256, 0, stream>>>(dtb, xcb, BCb, m_Alog + i*2048, nxt);
        scan_mid<<<dim3(BB, NST), 256, 0, stream>>>(nxt, Hinit);
        scan_fin<<<dim3(BB, NCH), 256, 0, stream>>>(dtb, xcb, BCb, xzb, m_Alog + i*2048, m_D + i*256, Hinit, ygbb);
        gemm_bf16<256,64><<<dim3(256, 1), 256, 0, stream>>>(ygbb, wbf + 196608 + (long)i*32768, cur, nxt, 128);
        cur = nxt;
        nxt = (i == 0) ? fusedB : fusedA;
    }
    // cur == fusedA here (A -> B -> A). xz region now dead -> decoder buffers.
    zpad<<<1056, 256, 0, stream>>>(tb_pad, 2048, 34);     // 16*128 planes
    zpad<<<1040, 256, 0, stream>>>(c1b_pad, 1024, 66);    // 16*64 planes
    ln_kernel<<<NROWS, 64, 0, stream>>>(cur, lnf_g, lnf_b, tb_pad, 1);
    prep_weff<<<32, 256, 0, stream>>>(c1_w, weff1, 64*128);
    prep_weff<<<8, 256, 0, stream>>>(c2_w, weff2, 32*64);
    conv_up2_lw<128, 32, 1><<<dim3(8, 4, 16), 256, 0, stream>>>(tb_pad, weff1, c1_b, bn1_g, bn1_b, bn1_m, bn1_v, c1b_pad, 0, 64);
    conv_up2_lw<64, 64, 0><<<dim3(32, 2, 16), 256, 0, stream>>>(c1b_pad, weff2, c2_b, bn2_g, bn2_b, bn2_m, bn2_v, vb, 1, 32);
    cce_add<<<dim3(64, 16), 256, 0, stream>>>(orig_x, orig_y, cce_w2, gates, vb);
    conv3_sig<<<dim3(64, 16), 256, 0, stream>>>(vb, c3_w, c3_b, (float*)d_out);
}